// Round 6
// baseline (540.843 us; speedup 1.0000x reference)
//
#include <hip/hip_runtime.h>
#include <math.h>

#define G 8
// 512 threads = 8 waves; wave w owns weight rows 3w..3w+2 (24 rows).
// Phase 2 reads x straight from GLOBAL (L2-resident) while wave w stages
// token w into a SINGLE 32KB LDS buffer for phase 4. No DMA, no double
// buffer, and no vmcnt wait at any barrier.
// LDS: 32KB xs + 768B hraw + 32B ss + 512B M ~= 33.3KB -> 4 blocks/CU
// -> 32 waves/CU (8/SIMD): 4 phase-independent convoys per CU.
// VGPR shape proven 64 in R5 (wreg 48 + ~16 working); waves_per_eu(6,8)
// caps at ~85 so no spill is possible.

__device__ __forceinline__ float sigmoidf_(float s) {
    return 1.0f / (1.0f + __expf(-s));
}

// Pair-fold reduction step: lanes with (l&m)==0 get X(l)+X(l^m),
// lanes with (l&m)!=0 get Y(l)+Y(l^m).
__device__ __forceinline__ float fold_(float X, float Y, int m, int l) {
    const bool hi = (l & m) != 0;
    const float a = hi ? Y : X;
    const float b = hi ? X : Y;
    return a + __shfl_xor(b, m);
}

// x += dpp_permute(x): single VALU op, replaces a ds_swizzle shuffle.
// Pairings (row_mirror / row_half_mirror / quad perms) are fixed-point-free
// involutions within 16-lane groups -> exact same group sums as xor8/4/2/1.
template <int CTRL>
__device__ __forceinline__ float dppadd_(float x) {
    const int xi = __float_as_int(x);
    const int yi = __builtin_amdgcn_update_dpp(0, xi, CTRL, 0xF, 0xF, true);
    return x + __int_as_float(yi);
}
#define DPP_ROW_MIRROR      0x140   // i <-> 15-i  (xor8-equivalent)
#define DPP_ROW_HALF_MIRROR 0x141   // i <-> 7-i   (xor4-equivalent)
#define DPP_QUAD_XOR2       0x4E    // quad_perm [2,3,0,1]
#define DPP_QUAD_XOR1       0xB1    // quad_perm [1,0,3,2]

__global__ __launch_bounds__(512)
__attribute__((amdgpu_waves_per_eu(6, 8)))
void fused_route_mix(const float* __restrict__ x,
                     const float* __restrict__ scale,
                     const float* __restrict__ w_pre,
                     const float* __restrict__ w_post,
                     const float* __restrict__ w_res,
                     const float* __restrict__ ap_p,
                     const float* __restrict__ apo_p,
                     const float* __restrict__ ar_p,
                     const float* __restrict__ b_pre,
                     const float* __restrict__ b_post,
                     const float* __restrict__ b_res,
                     float* __restrict__ out,
                     int rounds)
{
    __shared__ __align__(16) float xs[G * 1024];   // raw x, staged during phase 2
    __shared__ __align__(16) float hraw[G * 24];   // 24 raw dots per token
    __shared__ float sslds[G];                     // sum of squares per token
    __shared__ __align__(16) float Mlds[G * 16];   // 4x4 mixing matrix per token

    const int t = threadIdx.x;
    const int w = t >> 6;   // wave 0..7
    const int l = t & 63;   // lane 0..63

    // ---- once per block: 3 weight rows per wave, scale folded in ----
    // lane l owns elements {4l + 256mp + j : mp=0..3, j=0..3}.
    float wreg[3][16];
    #pragma unroll
    for (int rr = 0; rr < 3; ++rr) {
        const int k = 3 * w + rr;
        const float* wp = (k < 4) ? (w_pre + (size_t)k * 1024)
                        : (k < 8) ? (w_post + (size_t)(k - 4) * 1024)
                                  : (w_res + (size_t)(k - 8) * 1024);
        #pragma unroll
        for (int mp = 0; mp < 4; ++mp)
            #pragma unroll
            for (int j = 0; j < 4; ++j)
                wreg[rr][4 * mp + j] =
                    wp[4 * l + 256 * mp + j] * scale[4 * l + 256 * mp + j];
    }

    const float a_pre = ap_p[0], a_post = apo_p[0], a_res = ar_p[0];
    float4* const xs4 = (float4*)xs;

    for (int r = blockIdx.x; r < rounds; r += gridDim.x) {
        const size_t base = (size_t)r * (G * 1024);
        const float4* __restrict__ xg = (const float4*)(x + base);

        // B1: all waves finished last round's phase-4 LDS reads -> xs reusable.
        // lgkm-only; global stores/loads never block a barrier.
        asm volatile("s_waitcnt lgkmcnt(0)\n\ts_barrier" ::: "memory");

        // ---- phase 2: dots from GLOBAL; wave w stages token w to LDS ----
        #pragma unroll 2
        for (int i = 0; i < G; ++i) {
            float p0 = 0.f, p1 = 0.f, p2 = 0.f, ss = 0.f;
            const bool stage = (i == w);
            #pragma unroll
            for (int mp = 0; mp < 4; ++mp) {
                const float4 xv = xg[(i << 8) + (mp << 6) + l];  // coalesced, L2-hit
                if (stage)
                    xs4[(i << 8) + (mp << 6) + l] = xv;          // ds_write_b128
                const float xe[4] = {xv.x, xv.y, xv.z, xv.w};
                #pragma unroll
                for (int j = 0; j < 4; ++j) {
                    const float xj = xe[j];
                    p0 = fmaf(xj, wreg[0][4 * mp + j], p0);
                    p1 = fmaf(xj, wreg[1][4 * mp + j], p1);
                    p2 = fmaf(xj, wreg[2][4 * mp + j], p2);
                    ss = fmaf(xj, xj, ss);        // only wave 0 stores it
                }
            }
            // pack-fold: 3 cross-lane shuffles + 4 DPP adds (was 7 shuffles)
            const float q0 = fold_(p0, p1, 32, l);
            const float q1 = fold_(p2, ss, 32, l);
            float s = fold_(q0, q1, 16, l);
            s = dppadd_<DPP_ROW_MIRROR>(s);        // xor8-equivalent
            s = dppadd_<DPP_ROW_HALF_MIRROR>(s);   // xor4-equivalent
            s = dppadd_<DPP_QUAD_XOR2>(s);         // xor2
            s = dppadd_<DPP_QUAD_XOR1>(s);         // xor1
            // lane 0 -> p0, lane 32 -> p1, lane 16 -> p2, lane 48 -> ss
            if ((l & 15) == 0) {
                const int vid = ((l >> 5) & 1) | (((l >> 4) & 1) << 1);
                if (vid < 3) hraw[i * 24 + 3 * w + vid] = s;
                else if (w == 0) sslds[i] = s;
            }
        }

        // B2: hraw + xs staging writes visible. lgkm-only.
        asm volatile("s_waitcnt lgkmcnt(0)\n\ts_barrier" ::: "memory");

        // ---- phase 3: sinkhorn on wave 0 only (lane -> token l&7) ----
        if (w == 0) {
            const int tk = l & (G - 1);
            const float inv = rsqrtf(sslds[tk] * (1.0f / 1024.0f) + 1e-5f);
            float hr[24];
            const float4* __restrict__ hp = (const float4*)(hraw + tk * 24);
            #pragma unroll
            for (int q = 0; q < 6; ++q) {
                const float4 hv = hp[q];
                hr[4 * q + 0] = hv.x; hr[4 * q + 1] = hv.y;
                hr[4 * q + 2] = hv.z; hr[4 * q + 3] = hv.w;
            }

            float hpre[4], hpost[4];
            #pragma unroll
            for (int j = 0; j < 4; ++j)
                hpre[j] = sigmoidf_(fmaf(a_pre * inv, hr[j], b_pre[j]));
            #pragma unroll
            for (int i = 0; i < 4; ++i)
                hpost[i] = 2.0f * sigmoidf_(fmaf(a_post * inv, hr[4 + i], b_post[i]));

            float K[4][4];
            float mx = -1e30f;
            #pragma unroll
            for (int i = 0; i < 4; ++i)
                #pragma unroll
                for (int j = 0; j < 4; ++j) {
                    const float vv = fmaf(a_res * inv, hr[8 + 4 * i + j], b_res[4 * i + j]);
                    K[i][j] = vv;
                    mx = fmaxf(mx, vv);
                }
            #pragma unroll
            for (int i = 0; i < 4; ++i)
                #pragma unroll
                for (int j = 0; j < 4; ++j)
                    K[i][j] = __expf(K[i][j] - mx);

            // sinkhorn as scaling vectors: matrix is u_i * K_ij * v_j throughout.
            float u[4] = {1.f, 1.f, 1.f, 1.f};
            float v[4] = {1.f, 1.f, 1.f, 1.f};
            for (int it = 0; it < 20; ++it) {
                #pragma unroll
                for (int j = 0; j < 4; ++j) {
                    const float S = (fmaf(u[0], K[0][j], u[1] * K[1][j]))
                                  + (fmaf(u[2], K[2][j], u[3] * K[3][j]));
                    v[j] = v[j] * __builtin_amdgcn_rcpf(fmaf(v[j], S, 1e-8f));
                }
                #pragma unroll
                for (int i = 0; i < 4; ++i) {
                    const float T = (fmaf(K[i][0], v[0], K[i][1] * v[1]))
                                  + (fmaf(K[i][2], v[2], K[i][3] * v[3]));
                    u[i] = u[i] * __builtin_amdgcn_rcpf(fmaf(u[i], T, 1e-8f));
                }
            }

            if (l < G) {   // lane l computed token l exactly
                float4* Md = (float4*)(Mlds + (l << 4));
                #pragma unroll
                for (int i2 = 0; i2 < 4; ++i2) {
                    float4 row;
                    row.x = fmaf(u[i2] * K[i2][0], v[0], hpost[i2] * hpre[0]);
                    row.y = fmaf(u[i2] * K[i2][1], v[1], hpost[i2] * hpre[1]);
                    row.z = fmaf(u[i2] * K[i2][2], v[2], hpost[i2] * hpre[2]);
                    row.w = fmaf(u[i2] * K[i2][3], v[3], hpost[i2] * hpre[3]);
                    Md[i2] = row;
                }
            }
        }

        // B3: Mlds visible. lgkm-only.
        asm volatile("s_waitcnt lgkmcnt(0)\n\ts_barrier" ::: "memory");

        // ---- phase 4: wave w -> stream (w&3), tokens {2*ii + (w>>2)} ----
        const int s4 = w & 3;
        const int ihalf = w >> 2;
        #pragma unroll 2
        for (int ii = 0; ii < 4; ++ii) {
            const int i = (ii << 1) + ihalf;
            const float4 m4 = ((const float4*)Mlds)[(i << 2) + s4];  // broadcast
            const float4* __restrict__ xt = xs4 + (i << 8);
            const float4 a0 = xt[0 * 64 + l];
            const float4 a1 = xt[1 * 64 + l];
            const float4 a2 = xt[2 * 64 + l];
            const float4 a3 = xt[3 * 64 + l];
            float4 o;
            o.x = m4.x * a0.x + m4.y * a1.x + m4.z * a2.x + m4.w * a3.x;
            o.y = m4.x * a0.y + m4.y * a1.y + m4.z * a2.y + m4.w * a3.y;
            o.z = m4.x * a0.z + m4.y * a1.z + m4.z * a2.z + m4.w * a3.z;
            o.w = m4.x * a0.w + m4.y * a1.w + m4.z * a2.w + m4.w * a3.w;
            ((float4*)(out + base))[(i << 8) + (s4 << 6) + l] = o;
        }
    }
}

extern "C" void kernel_launch(void* const* d_in, const int* in_sizes, int n_in,
                              void* d_out, int out_size, void* d_ws, size_t ws_size,
                              hipStream_t stream) {
    const float* x      = (const float*)d_in[0];
    const float* scale  = (const float*)d_in[1];
    const float* w_pre  = (const float*)d_in[2];
    const float* w_post = (const float*)d_in[3];
    const float* w_res  = (const float*)d_in[4];
    const float* a_pre  = (const float*)d_in[5];
    const float* a_post = (const float*)d_in[6];
    const float* a_res  = (const float*)d_in[7];
    const float* b_pre  = (const float*)d_in[8];
    const float* b_post = (const float*)d_in[9];
    const float* b_res  = (const float*)d_in[10];
    float* out = (float*)d_out;

    const int tokens = in_sizes[0] / 1024;   // B*T (n*C = 1024)
    const int rounds = tokens / G;           // 4096
    // 1024 blocks x 512 threads -> 4 blocks/CU on 256 CUs, 4 rounds each.
    const int grid = rounds < 1024 ? rounds : 1024;

    fused_route_mix<<<grid, 512, 0, stream>>>(
        x, scale, w_pre, w_post, w_res,
        a_pre, a_post, a_res, b_pre, b_post, b_res,
        out, rounds);
}

// Round 7
// 308.516 us; speedup vs baseline: 1.7530x; 1.7530x over previous
//
#include <hip/hip_runtime.h>
#include <math.h>

#define G 8
// 512 threads = 8 waves; wave w owns weight rows 3w..3w+2 (24 rows).
// Phase 2 reads x straight from GLOBAL (L2-resident) while wave w stages
// token w into a SINGLE 32KB LDS buffer for phase 4. No DMA, no double
// buffer, and no vmcnt wait at any barrier.
// LDS: 32KB xs + 768B hraw + 32B ss + 512B M ~= 33.6KB -> 4 blocks/CU.
// waves_per_eu(4,8): min=4 keeps the compiler's VGPR budget at 128 (the
// EXACT context in which R5's identical shape allocated 64 naturally, no
// spill); max=8 lets HW run 8 waves/EU = 32 waves/CU when VGPR<=64.
// R4/R6 lesson: never set min>4 (allocator retargets and spill-cascades).

__device__ __forceinline__ float sigmoidf_(float s) {
    return 1.0f / (1.0f + __expf(-s));
}

// Pair-fold reduction step: lanes with (l&m)==0 get X(l)+X(l^m),
// lanes with (l&m)!=0 get Y(l)+Y(l^m).
__device__ __forceinline__ float fold_(float X, float Y, int m, int l) {
    const bool hi = (l & m) != 0;
    const float a = hi ? Y : X;
    const float b = hi ? X : Y;
    return a + __shfl_xor(b, m);
}

__global__ __launch_bounds__(512)
__attribute__((amdgpu_waves_per_eu(4, 8)))
void fused_route_mix(const float* __restrict__ x,
                     const float* __restrict__ scale,
                     const float* __restrict__ w_pre,
                     const float* __restrict__ w_post,
                     const float* __restrict__ w_res,
                     const float* __restrict__ ap_p,
                     const float* __restrict__ apo_p,
                     const float* __restrict__ ar_p,
                     const float* __restrict__ b_pre,
                     const float* __restrict__ b_post,
                     const float* __restrict__ b_res,
                     float* __restrict__ out,
                     int rounds)
{
    __shared__ __align__(16) float xs[G * 1024];   // raw x, staged during phase 2
    __shared__ __align__(16) float hraw[G * 24];   // 24 raw dots per token
    __shared__ float sslds[G];                     // sum of squares per token
    __shared__ __align__(16) float Mlds[G * 16];   // 4x4 mixing matrix per token

    const int t = threadIdx.x;
    const int w = t >> 6;   // wave 0..7
    const int l = t & 63;   // lane 0..63

    // ---- once per block: 3 weight rows per wave, scale folded in ----
    // lane l owns elements {4l + 256mp + j : mp=0..3, j=0..3}.
    float wreg[3][16];
    #pragma unroll
    for (int rr = 0; rr < 3; ++rr) {
        const int k = 3 * w + rr;
        const float* wp = (k < 4) ? (w_pre + (size_t)k * 1024)
                        : (k < 8) ? (w_post + (size_t)(k - 4) * 1024)
                                  : (w_res + (size_t)(k - 8) * 1024);
        #pragma unroll
        for (int mp = 0; mp < 4; ++mp)
            #pragma unroll
            for (int j = 0; j < 4; ++j)
                wreg[rr][4 * mp + j] =
                    wp[4 * l + 256 * mp + j] * scale[4 * l + 256 * mp + j];
    }

    const float a_pre = ap_p[0], a_post = apo_p[0], a_res = ar_p[0];
    float4* const xs4 = (float4*)xs;

    for (int r = blockIdx.x; r < rounds; r += gridDim.x) {
        const size_t base = (size_t)r * (G * 1024);
        const float4* __restrict__ xg = (const float4*)(x + base);

        // B1: all waves finished last round's phase-4 LDS reads -> xs reusable.
        // lgkm-only; global stores/loads never block a barrier.
        asm volatile("s_waitcnt lgkmcnt(0)\n\ts_barrier" ::: "memory");

        // ---- phase 2: dots from GLOBAL; wave w stages token w to LDS ----
        #pragma unroll 2
        for (int i = 0; i < G; ++i) {
            float p0 = 0.f, p1 = 0.f, p2 = 0.f, ss = 0.f;
            const bool stage = (i == w);
            #pragma unroll
            for (int mp = 0; mp < 4; ++mp) {
                const float4 xv = xg[(i << 8) + (mp << 6) + l];  // coalesced, L2-hit
                if (stage)
                    xs4[(i << 8) + (mp << 6) + l] = xv;          // ds_write_b128
                const float xe[4] = {xv.x, xv.y, xv.z, xv.w};
                #pragma unroll
                for (int j = 0; j < 4; ++j) {
                    const float xj = xe[j];
                    p0 = fmaf(xj, wreg[0][4 * mp + j], p0);
                    p1 = fmaf(xj, wreg[1][4 * mp + j], p1);
                    p2 = fmaf(xj, wreg[2][4 * mp + j], p2);
                    ss = fmaf(xj, xj, ss);        // only wave 0 stores it
                }
            }
            // pack-fold butterfly: 7 shfl for 4 values
            const float q0 = fold_(p0, p1, 32, l);
            const float q1 = fold_(p2, ss, 32, l);
            float s = fold_(q0, q1, 16, l);
            s += __shfl_xor(s, 8);
            s += __shfl_xor(s, 4);
            s += __shfl_xor(s, 2);
            s += __shfl_xor(s, 1);
            // lane 0 -> p0, lane 32 -> p1, lane 16 -> p2, lane 48 -> ss
            if ((l & 15) == 0) {
                const int vid = ((l >> 5) & 1) | (((l >> 4) & 1) << 1);
                if (vid < 3) hraw[i * 24 + 3 * w + vid] = s;
                else if (w == 0) sslds[i] = s;
            }
        }

        // B2: hraw + xs staging writes visible. lgkm-only.
        asm volatile("s_waitcnt lgkmcnt(0)\n\ts_barrier" ::: "memory");

        // ---- phase 3: sinkhorn on wave 0 only (lane -> token l&7) ----
        if (w == 0) {
            const int tk = l & (G - 1);
            const float inv = rsqrtf(sslds[tk] * (1.0f / 1024.0f) + 1e-5f);
            float hr[24];
            const float4* __restrict__ hp = (const float4*)(hraw + tk * 24);
            #pragma unroll
            for (int q = 0; q < 6; ++q) {
                const float4 hv = hp[q];
                hr[4 * q + 0] = hv.x; hr[4 * q + 1] = hv.y;
                hr[4 * q + 2] = hv.z; hr[4 * q + 3] = hv.w;
            }

            float hpre[4], hpost[4];
            #pragma unroll
            for (int j = 0; j < 4; ++j)
                hpre[j] = sigmoidf_(fmaf(a_pre * inv, hr[j], b_pre[j]));
            #pragma unroll
            for (int i = 0; i < 4; ++i)
                hpost[i] = 2.0f * sigmoidf_(fmaf(a_post * inv, hr[4 + i], b_post[i]));

            float K[4][4];
            float mx = -1e30f;
            #pragma unroll
            for (int i = 0; i < 4; ++i)
                #pragma unroll
                for (int j = 0; j < 4; ++j) {
                    const float vv = fmaf(a_res * inv, hr[8 + 4 * i + j], b_res[4 * i + j]);
                    K[i][j] = vv;
                    mx = fmaxf(mx, vv);
                }
            #pragma unroll
            for (int i = 0; i < 4; ++i)
                #pragma unroll
                for (int j = 0; j < 4; ++j)
                    K[i][j] = __expf(K[i][j] - mx);

            // sinkhorn as scaling vectors: matrix is u_i * K_ij * v_j throughout.
            float u[4] = {1.f, 1.f, 1.f, 1.f};
            float v[4] = {1.f, 1.f, 1.f, 1.f};
            for (int it = 0; it < 20; ++it) {
                #pragma unroll
                for (int j = 0; j < 4; ++j) {
                    const float S = (fmaf(u[0], K[0][j], u[1] * K[1][j]))
                                  + (fmaf(u[2], K[2][j], u[3] * K[3][j]));
                    v[j] = v[j] * __builtin_amdgcn_rcpf(fmaf(v[j], S, 1e-8f));
                }
                #pragma unroll
                for (int i = 0; i < 4; ++i) {
                    const float T = (fmaf(K[i][0], v[0], K[i][1] * v[1]))
                                  + (fmaf(K[i][2], v[2], K[i][3] * v[3]));
                    u[i] = u[i] * __builtin_amdgcn_rcpf(fmaf(u[i], T, 1e-8f));
                }
            }

            if (l < G) {   // lane l computed token l exactly
                float4* Md = (float4*)(Mlds + (l << 4));
                #pragma unroll
                for (int i2 = 0; i2 < 4; ++i2) {
                    float4 row;
                    row.x = fmaf(u[i2] * K[i2][0], v[0], hpost[i2] * hpre[0]);
                    row.y = fmaf(u[i2] * K[i2][1], v[1], hpost[i2] * hpre[1]);
                    row.z = fmaf(u[i2] * K[i2][2], v[2], hpost[i2] * hpre[2]);
                    row.w = fmaf(u[i2] * K[i2][3], v[3], hpost[i2] * hpre[3]);
                    Md[i2] = row;
                }
            }
        }

        // B3: Mlds visible. lgkm-only.
        asm volatile("s_waitcnt lgkmcnt(0)\n\ts_barrier" ::: "memory");

        // ---- phase 4: wave w -> stream (w&3), tokens {2*ii + (w>>2)} ----
        const int s4 = w & 3;
        const int ihalf = w >> 2;
        #pragma unroll 2
        for (int ii = 0; ii < 4; ++ii) {
            const int i = (ii << 1) + ihalf;
            const float4 m4 = ((const float4*)Mlds)[(i << 2) + s4];  // broadcast
            const float4* __restrict__ xt = xs4 + (i << 8);
            const float4 a0 = xt[0 * 64 + l];
            const float4 a1 = xt[1 * 64 + l];
            const float4 a2 = xt[2 * 64 + l];
            const float4 a3 = xt[3 * 64 + l];
            float4 o;
            o.x = m4.x * a0.x + m4.y * a1.x + m4.z * a2.x + m4.w * a3.x;
            o.y = m4.x * a0.y + m4.y * a1.y + m4.z * a2.y + m4.w * a3.y;
            o.z = m4.x * a0.z + m4.y * a1.z + m4.z * a2.z + m4.w * a3.z;
            o.w = m4.x * a0.w + m4.y * a1.w + m4.z * a2.w + m4.w * a3.w;
            ((float4*)(out + base))[(i << 8) + (s4 << 6) + l] = o;
        }
    }
}

extern "C" void kernel_launch(void* const* d_in, const int* in_sizes, int n_in,
                              void* d_out, int out_size, void* d_ws, size_t ws_size,
                              hipStream_t stream) {
    const float* x      = (const float*)d_in[0];
    const float* scale  = (const float*)d_in[1];
    const float* w_pre  = (const float*)d_in[2];
    const float* w_post = (const float*)d_in[3];
    const float* w_res  = (const float*)d_in[4];
    const float* a_pre  = (const float*)d_in[5];
    const float* a_post = (const float*)d_in[6];
    const float* a_res  = (const float*)d_in[7];
    const float* b_pre  = (const float*)d_in[8];
    const float* b_post = (const float*)d_in[9];
    const float* b_res  = (const float*)d_in[10];
    float* out = (float*)d_out;

    const int tokens = in_sizes[0] / 1024;   // B*T (n*C = 1024)
    const int rounds = tokens / G;           // 4096
    // 1024 blocks x 512 threads -> 4 blocks/CU on 256 CUs, 4 rounds each.
    const int grid = rounds < 1024 ? rounds : 1024;

    fused_route_mix<<<grid, 512, 0, stream>>>(
        x, scale, w_pre, w_post, w_res,
        a_pre, a_post, a_res, b_pre, b_post, b_res,
        out, rounds);
}

// Round 8
// 304.638 us; speedup vs baseline: 1.7754x; 1.0127x over previous
//
#include <hip/hip_runtime.h>
#include <math.h>

// ============ two-kernel split ============
// A (route_k): x -> M[token][16]  (2MB into d_ws). 512thr/8 waves, 3 rows/wave
//   (VGPR-64-proven shape), G=16 tokens/round, ONE lgkm-only barrier per round,
//   sinkhorn rotated across waves and overlapped with next round's dots via
//   double-buffered hraw. LDS 3.6KB -> 4 blocks/CU (thread-capped).
// B (mix_k): out[tok] = M[tok] * x[tok]. Wave-per-token, no barriers, no LDS,
//   pure stream at HBM rate.

#define GA 16

__device__ __forceinline__ float sigmoidf_(float s) {
    return 1.0f / (1.0f + __expf(-s));
}

// Pair-fold reduction step: lanes with (l&m)==0 get X(l)+X(l^m),
// lanes with (l&m)!=0 get Y(l)+Y(l^m).
__device__ __forceinline__ float fold_(float X, float Y, int m, int l) {
    const bool hi = (l & m) != 0;
    const float a = hi ? Y : X;
    const float b = hi ? X : Y;
    return a + __shfl_xor(b, m);
}

__global__ __launch_bounds__(512)
__attribute__((amdgpu_waves_per_eu(4, 8)))   // R7: this context -> natural VGPR=64, no spill
void route_k(const float* __restrict__ x,
             const float* __restrict__ scale,
             const float* __restrict__ w_pre,
             const float* __restrict__ w_post,
             const float* __restrict__ w_res,
             const float* __restrict__ ap_p,
             const float* __restrict__ apo_p,
             const float* __restrict__ ar_p,
             const float* __restrict__ b_pre,
             const float* __restrict__ b_post,
             const float* __restrict__ b_res,
             float* __restrict__ Mout,
             int rounds)
{
    // hraw[parity][token][28]: dots 0..23, ss at 24 (stride 28 keeps float4 align)
    __shared__ float hraw[2][GA * 28];

    const int t = threadIdx.x;
    const int w = t >> 6;   // wave 0..7
    const int l = t & 63;   // lane 0..63

    // 3 weight rows per wave, scale folded in; lane l owns {4l+256mp+j}.
    float wreg[3][16];
    #pragma unroll
    for (int rr = 0; rr < 3; ++rr) {
        const int k = 3 * w + rr;
        const float* wp = (k < 4) ? (w_pre + (size_t)k * 1024)
                        : (k < 8) ? (w_post + (size_t)(k - 4) * 1024)
                                  : (w_res + (size_t)(k - 8) * 1024);
        #pragma unroll
        for (int mp = 0; mp < 4; ++mp)
            #pragma unroll
            for (int j = 0; j < 4; ++j)
                wreg[rr][4 * mp + j] =
                    wp[4 * l + 256 * mp + j] * scale[4 * l + 256 * mp + j];
    }

    int lr = 0;
    for (int r = blockIdx.x; r < rounds; r += gridDim.x, ++lr) {
        const float4* __restrict__ xg = (const float4*)(x + (size_t)r * (GA * 1024));
        float* __restrict__ hb = hraw[lr & 1];

        // ---- dots: 3 proj rows + ss per wave per token, straight from global ----
        #pragma unroll 2
        for (int i = 0; i < GA; ++i) {
            float p0 = 0.f, p1 = 0.f, p2 = 0.f, ss = 0.f;
            #pragma unroll
            for (int mp = 0; mp < 4; ++mp) {
                const float4 xv = xg[(i << 8) + (mp << 6) + l];  // coalesced
                const float xe[4] = {xv.x, xv.y, xv.z, xv.w};
                #pragma unroll
                for (int j = 0; j < 4; ++j) {
                    const float xj = xe[j];
                    p0 = fmaf(xj, wreg[0][4 * mp + j], p0);
                    p1 = fmaf(xj, wreg[1][4 * mp + j], p1);
                    p2 = fmaf(xj, wreg[2][4 * mp + j], p2);
                    ss = fmaf(xj, xj, ss);
                }
            }
            // pack-fold butterfly: 7 shfl for 4 values
            const float q0 = fold_(p0, p1, 32, l);
            const float q1 = fold_(p2, ss, 32, l);
            float s = fold_(q0, q1, 16, l);
            s += __shfl_xor(s, 8);
            s += __shfl_xor(s, 4);
            s += __shfl_xor(s, 2);
            s += __shfl_xor(s, 1);
            // lane 0 -> p0, lane 32 -> p1, lane 16 -> p2, lane 48 -> ss
            if ((l & 15) == 0) {
                const int vid = ((l >> 5) & 1) | (((l >> 4) & 1) << 1);
                if (vid < 3) hb[i * 28 + 3 * w + vid] = s;
                else if (w == 0) hb[i * 28 + 24] = s;
            }
        }

        // ONE barrier per round (lgkm-only: global loads never drained here)
        asm volatile("s_waitcnt lgkmcnt(0)\n\ts_barrier" ::: "memory");

        // ---- sinkhorn: rotating wave; overlaps others' next-round dots ----
        if (w == (lr & 7)) {
            const int tk = l & (GA - 1);
            const float* __restrict__ hp = hb + tk * 28;
            float hr[24];
            #pragma unroll
            for (int q = 0; q < 6; ++q) {
                const float4 hv = ((const float4*)hp)[q];
                hr[4 * q + 0] = hv.x; hr[4 * q + 1] = hv.y;
                hr[4 * q + 2] = hv.z; hr[4 * q + 3] = hv.w;
            }
            const float inv = rsqrtf(hp[24] * (1.0f / 1024.0f) + 1e-5f);
            const float a_pre = ap_p[0], a_post = apo_p[0], a_res = ar_p[0];

            float hpre[4], hpost[4];
            #pragma unroll
            for (int j = 0; j < 4; ++j)
                hpre[j] = sigmoidf_(fmaf(a_pre * inv, hr[j], b_pre[j]));
            #pragma unroll
            for (int i = 0; i < 4; ++i)
                hpost[i] = 2.0f * sigmoidf_(fmaf(a_post * inv, hr[4 + i], b_post[i]));

            float K[4][4];
            float mx = -1e30f;
            #pragma unroll
            for (int i = 0; i < 4; ++i)
                #pragma unroll
                for (int j = 0; j < 4; ++j) {
                    const float vv = fmaf(a_res * inv, hr[8 + 4 * i + j], b_res[4 * i + j]);
                    K[i][j] = vv;
                    mx = fmaxf(mx, vv);
                }
            #pragma unroll
            for (int i = 0; i < 4; ++i)
                #pragma unroll
                for (int j = 0; j < 4; ++j)
                    K[i][j] = __expf(K[i][j] - mx);

            // sinkhorn as scaling vectors: matrix is u_i * K_ij * v_j throughout.
            float u[4] = {1.f, 1.f, 1.f, 1.f};
            float v[4] = {1.f, 1.f, 1.f, 1.f};
            for (int it = 0; it < 20; ++it) {
                #pragma unroll
                for (int j = 0; j < 4; ++j) {
                    const float S = (fmaf(u[0], K[0][j], u[1] * K[1][j]))
                                  + (fmaf(u[2], K[2][j], u[3] * K[3][j]));
                    v[j] = v[j] * __builtin_amdgcn_rcpf(fmaf(v[j], S, 1e-8f));
                }
                #pragma unroll
                for (int i = 0; i < 4; ++i) {
                    const float T = (fmaf(K[i][0], v[0], K[i][1] * v[1]))
                                  + (fmaf(K[i][2], v[2], K[i][3] * v[3]));
                    u[i] = u[i] * __builtin_amdgcn_rcpf(fmaf(u[i], T, 1e-8f));
                }
            }

            if (l < GA) {   // lane l computed token l exactly
                float4* __restrict__ Md =
                    (float4*)(Mout + ((size_t)r * GA + tk) * 16);
                #pragma unroll
                for (int i2 = 0; i2 < 4; ++i2) {
                    float4 row;
                    row.x = fmaf(u[i2] * K[i2][0], v[0], hpost[i2] * hpre[0]);
                    row.y = fmaf(u[i2] * K[i2][1], v[1], hpost[i2] * hpre[1]);
                    row.z = fmaf(u[i2] * K[i2][2], v[2], hpost[i2] * hpre[2]);
                    row.w = fmaf(u[i2] * K[i2][3], v[3], hpost[i2] * hpre[3]);
                    Md[i2] = row;
                }
            }
        }
        // No second barrier: next round writes hraw[lr^1]; hraw[lr&1] is only
        // overwritten two rounds later, after the sinkhorn wave has passed the
        // next barrier.
    }
}

// ---- kernel B: pure streaming mix, wave-per-token, no barriers, no LDS ----
__global__ __launch_bounds__(512)
void mix_k(const float* __restrict__ x,
           const float* __restrict__ M,
           float* __restrict__ out,
           int ntok)
{
    const int l = threadIdx.x & 63;
    const int gw = (int)((blockIdx.x * 512u + threadIdx.x) >> 6);
    const int nw = (int)((gridDim.x * 512u) >> 6);

    for (int tok = gw; tok < ntok; tok += nw) {
        const float4* __restrict__ xt = (const float4*)(x + (size_t)tok * 1024);
        const float4* __restrict__ Mt = (const float4*)(M + (size_t)tok * 16);
        const float4 m0 = Mt[0], m1 = Mt[1], m2 = Mt[2], m3 = Mt[3];
        const float4 a0 = xt[0 * 64 + l];
        const float4 a1 = xt[1 * 64 + l];
        const float4 a2 = xt[2 * 64 + l];
        const float4 a3 = xt[3 * 64 + l];
        float4* __restrict__ ot = (float4*)(out + (size_t)tok * 1024);
        float4 o0, o1, o2, o3;
        o0.x = m0.x*a0.x + m0.y*a1.x + m0.z*a2.x + m0.w*a3.x;
        o0.y = m0.x*a0.y + m0.y*a1.y + m0.z*a2.y + m0.w*a3.y;
        o0.z = m0.x*a0.z + m0.y*a1.z + m0.z*a2.z + m0.w*a3.z;
        o0.w = m0.x*a0.w + m0.y*a1.w + m0.z*a2.w + m0.w*a3.w;
        o1.x = m1.x*a0.x + m1.y*a1.x + m1.z*a2.x + m1.w*a3.x;
        o1.y = m1.x*a0.y + m1.y*a1.y + m1.z*a2.y + m1.w*a3.y;
        o1.z = m1.x*a0.z + m1.y*a1.z + m1.z*a2.z + m1.w*a3.z;
        o1.w = m1.x*a0.w + m1.y*a1.w + m1.z*a2.w + m1.w*a3.w;
        o2.x = m2.x*a0.x + m2.y*a1.x + m2.z*a2.x + m2.w*a3.x;
        o2.y = m2.x*a0.y + m2.y*a1.y + m2.z*a2.y + m2.w*a3.y;
        o2.z = m2.x*a0.z + m2.y*a1.z + m2.z*a2.z + m2.w*a3.z;
        o2.w = m2.x*a0.w + m2.y*a1.w + m2.z*a2.w + m2.w*a3.w;
        o3.x = m3.x*a0.x + m3.y*a1.x + m3.z*a2.x + m3.w*a3.x;
        o3.y = m3.x*a0.y + m3.y*a1.y + m3.z*a2.y + m3.w*a3.y;
        o3.z = m3.x*a0.z + m3.y*a1.z + m3.z*a2.z + m3.w*a3.z;
        o3.w = m3.x*a0.w + m3.y*a1.w + m3.z*a2.w + m3.w*a3.w;
        ot[0 * 64 + l] = o0;
        ot[1 * 64 + l] = o1;
        ot[2 * 64 + l] = o2;
        ot[3 * 64 + l] = o3;
    }
}

extern "C" void kernel_launch(void* const* d_in, const int* in_sizes, int n_in,
                              void* d_out, int out_size, void* d_ws, size_t ws_size,
                              hipStream_t stream) {
    const float* x      = (const float*)d_in[0];
    const float* scale  = (const float*)d_in[1];
    const float* w_pre  = (const float*)d_in[2];
    const float* w_post = (const float*)d_in[3];
    const float* w_res  = (const float*)d_in[4];
    const float* a_pre  = (const float*)d_in[5];
    const float* a_post = (const float*)d_in[6];
    const float* a_res  = (const float*)d_in[7];
    const float* b_pre  = (const float*)d_in[8];
    const float* b_post = (const float*)d_in[9];
    const float* b_res  = (const float*)d_in[10];
    float* out  = (float*)d_out;
    float* Mbuf = (float*)d_ws;              // tokens*16 floats = 2MB

    const int tokens = in_sizes[0] / 1024;   // B*T (n*C = 1024)
    const int roundsA = tokens / GA;         // 2048
    const int gridA = roundsA < 1024 ? roundsA : 1024;

    route_k<<<gridA, 512, 0, stream>>>(
        x, scale, w_pre, w_post, w_res,
        a_pre, a_post, a_res, b_pre, b_post, b_res,
        Mbuf, roundsA);

    mix_k<<<1024, 512, 0, stream>>>(x, Mbuf, out, tokens);
}